// Round 3
// baseline (436.974 us; speedup 1.0000x reference)
//
#include <hip/hip_runtime.h>
#include <cstdint>
#include <cstddef>

typedef __attribute__((ext_vector_type(8))) short bf16x8;
typedef __attribute__((ext_vector_type(4))) float f32x4;
typedef __attribute__((ext_vector_type(4))) int i32x4;

#define HALO_W   18
#define PLANEPAD 181   // i32x4 per octet plane (180 px + 1 pad); 181*16B stride

__device__ inline unsigned short cvt_bf16_rne(float f) {
    unsigned u = __builtin_bit_cast(unsigned, f);
    u = (u + 0x7FFFu + ((u >> 16) & 1u)) >> 16;
    return (unsigned short)u;
}

// ---------------------------------------------------------------------------
// prep_kernel: fused conv_first (blocks 0..1023) + weight pack for layers
// 1..3 (blocks 1024..1239) + mask-format detect (block 1240). 256 threads.
__global__ void prep_kernel(const float* __restrict__ img,
                            const float* __restrict__ cw0,
                            const float* __restrict__ cb0,
                            unsigned short* __restrict__ act,
                            const float* __restrict__ cw1,
                            const float* __restrict__ cw2,
                            const float* __restrict__ cw3,
                            char* __restrict__ apack,
                            const unsigned int* __restrict__ mask,
                            int* __restrict__ flag) {
    int bid = blockIdx.x, tid = threadIdx.x;

    if (bid < 1024) {
        // ---- layer 0: 1 -> 64 + ReLU, out bf16 [a][row][col][64]
        int y = bid & 255, a = bid >> 8, x = tid;
        float p[3][3];
        #pragma unroll
        for (int ty = 0; ty < 3; ++ty)
            #pragma unroll
            for (int tx = 0; tx < 3; ++tx) {
                int py = y + ty - 1, px = x + tx - 1;
                p[ty][tx] = ((unsigned)py < 256u && (unsigned)px < 256u)
                            ? img[py * 256 + px] : 0.0f;
            }
        const float* w = cw0 + (size_t)a * 64 * 9;
        const float* b = cb0 + a * 64;
        unsigned pk[32];
        #pragma unroll
        for (int co = 0; co < 64; ++co) {
            const float* wc = w + co * 9;
            float acc = b[co];
            #pragma unroll
            for (int ty = 0; ty < 3; ++ty)
                #pragma unroll
                for (int tx = 0; tx < 3; ++tx)
                    acc = fmaf(wc[ty * 3 + tx], p[ty][tx], acc);
            acc = fmaxf(acc, 0.0f);
            unsigned short hv = cvt_bf16_rne(acc);
            if (co & 1) pk[co >> 1] |= ((unsigned)hv << 16);
            else        pk[co >> 1] = (unsigned)hv;
        }
        char* ob = (char*)act + (((size_t)(a << 16) + (y << 8) + x) << 7);
        #pragma unroll
        for (int k = 0; k < 8; ++k)
            *(i32x4*)(ob + k * 16) = *(i32x4*)&pk[k * 4];
        return;
    }

    if (bid < 1240) {
        // ---- pack mid-layer weights to A-frag order:
        // idx = ((((a*2+ks)*9+tap)*4+mf)*64+lane), one i32x4 per idx, per layer.
        int idx = (bid - 1024) * 256 + tid;     // 0 .. 55295
        int layer = idx / 18432;
        int r = idx - layer * 18432;
        int lane = r & 63, mf = (r >> 6) & 3;
        int t = r >> 8;
        int tap = t % 9, t2 = t / 9;
        int ks = t2 & 1, a = t2 >> 1;
        int n = lane & 15, q = lane >> 4;
        int co = mf * 16 + n;
        int ci0 = ks * 32 + q * 8;
        const float* cw = (layer == 0) ? cw1 : (layer == 1) ? cw2 : cw3;
        unsigned d[4];
        #pragma unroll
        for (int jj = 0; jj < 4; ++jj) {
            unsigned short h0 = cvt_bf16_rne(cw[((size_t)(a * 64 + co) * 64 + ci0 + 2 * jj + 0) * 9 + tap]);
            unsigned short h1 = cvt_bf16_rne(cw[((size_t)(a * 64 + co) * 64 + ci0 + 2 * jj + 1) * 9 + tap]);
            d[jj] = (unsigned)h0 | ((unsigned)h1 << 16);
        }
        *(i32x4*)(apack + (size_t)idx * 16) = *(i32x4*)d;
        return;
    }

    // ---- mask format detect (single block): 0=int32, 1=bytes, 2=float
    __shared__ int red;
    if (tid == 0) red = 0;
    __syncthreads();
    int f = 0;
    for (int k = 0; k < 128; ++k) {
        unsigned v = mask[k * 256 + tid];
        if (v == 0x3F800000u) f |= 2;
        else if (v > 1u) f |= 1;
    }
    if (f) atomicOr(&red, f);
    __syncthreads();
    if (tid == 0) *flag = red;
}

// ---------------------------------------------------------------------------
// Mid layers 64->64 + ReLU via bf16 MFMA implicit GEMM.
// WG = 256 thr (4 waves), tile = 8 rows x 16 cols.
// LDS: octet-major [o 0..7][px 0..179], plane stride 181 i32x4.
// grid dim3(16, 32, 4) = 2048 WGs.
__global__ __launch_bounds__(256, 4)
void conv_mid_mfma(const unsigned short* __restrict__ act_in,
                   const char* __restrict__ apack_l,
                   const float* __restrict__ cb,
                   unsigned short* __restrict__ act_out) {
    __shared__ i32x4 lds4[8 * PLANEPAD];
    int tid = threadIdx.x;
    int a = blockIdx.z;
    int r0 = blockIdx.y * 8, c0 = blockIdx.x * 16;
    const char* actb = (const char*)act_in;

    // stage 10x18 halo tile (1440 data i32x4, +8 tail to pad) coalesced
    for (int s = tid; s < 1448; s += 256) {
        int o = s & 7, px = s >> 3;
        int prow = px / HALO_W;
        int pcol = px - prow * HALO_W;
        int grow = r0 - 1 + prow, gcol = c0 - 1 + pcol;
        i32x4 v = {0, 0, 0, 0};
        if ((unsigned)grow < 256u && (unsigned)gcol < 256u)
            v = *(const i32x4*)(actb + (((size_t)(a << 16) + (grow << 8) + gcol) << 7) + (o << 4));
        lds4[o * PLANEPAD + px] = v;
    }
    __syncthreads();

    int lane = tid & 63, wv = tid >> 6;
    int n = lane & 15, q = lane >> 4;

    f32x4 acc[4][2];
    #pragma unroll
    for (int mf = 0; mf < 4; ++mf) {
        f32x4 bb = *(const f32x4*)(cb + a * 64 + mf * 16 + q * 4);
        acc[mf][0] = bb;
        acc[mf][1] = bb;
    }

    const char* ap = apack_l + (size_t)a * 73728 + lane * 16;

    #pragma unroll
    for (int ks = 0; ks < 2; ++ks) {
        const char* apk = ap + ks * 36864;
        int pbase = (ks * 4 + q) * PLANEPAD;
        #pragma unroll
        for (int tap = 0; tap < 9; ++tap) {
            const int ty = tap / 3, tx = tap - ty * 3;
            bf16x8 Af[4], Bf[2];
            #pragma unroll
            for (int mf = 0; mf < 4; ++mf)
                Af[mf] = __builtin_bit_cast(bf16x8,
                    *(const i32x4*)(apk + tap * 4096 + mf * 1024));
            #pragma unroll
            for (int nf = 0; nf < 2; ++nf) {
                int px = (wv * 2 + nf + ty) * HALO_W + n + tx;
                Bf[nf] = __builtin_bit_cast(bf16x8, lds4[pbase + px]);
            }
            #pragma unroll
            for (int mf = 0; mf < 4; ++mf)
                #pragma unroll
                for (int nf = 0; nf < 2; ++nf)
                    acc[mf][nf] = __builtin_amdgcn_mfma_f32_16x16x32_bf16(
                        Af[mf], Bf[nf], acc[mf][nf], 0, 0, 0);
        }
    }

    #pragma unroll
    for (int nf = 0; nf < 2; ++nf) {
        int grow = r0 + wv * 2 + nf;
        int gcol = c0 + n;
        char* ob = (char*)act_out + (((size_t)(a << 16) + (grow << 8) + gcol) << 7) + q * 8;
        #pragma unroll
        for (int mf = 0; mf < 4; ++mf) {
            f32x4 v = acc[mf][nf];
            unsigned d0 = (unsigned)cvt_bf16_rne(fmaxf(v.x, 0.0f))
                        | ((unsigned)cvt_bf16_rne(fmaxf(v.y, 0.0f)) << 16);
            unsigned d1 = (unsigned)cvt_bf16_rne(fmaxf(v.z, 0.0f))
                        | ((unsigned)cvt_bf16_rne(fmaxf(v.w, 0.0f)) << 16);
            uint2 st; st.x = d0; st.y = d1;
            *(uint2*)(ob + mf * 32) = st;
        }
    }
}

// ---------------------------------------------------------------------------
// Layer 4: 64 -> 1, no ReLU, fp32 out. 8 lanes/pixel, cheap bf16 decode
// (lo = d<<16, hi = d&0xFFFF0000). grid (256,4), 256 threads.
__global__ void conv_last_kernel(const unsigned short* __restrict__ act,
                                 const float* __restrict__ cw4,
                                 const float* __restrict__ cb4,
                                 float* __restrict__ W_a) {
    int y = blockIdx.x, a = blockIdx.y;
    int tid = threadIdx.x;
    int lane = tid & 63, wv = tid >> 6;
    int o = lane & 7, pl = lane >> 3;
    float wr[8][9];
    #pragma unroll
    for (int j = 0; j < 8; ++j) {
        const float* wp = cw4 + ((size_t)a * 64 + o * 8 + j) * 9;
        #pragma unroll
        for (int t = 0; t < 9; ++t) wr[j][t] = wp[t];
    }
    const char* actb = (const char*)act;
    float bias = cb4[a];
    for (int i = 0; i < 8; ++i) {
        int x = i * 32 + wv * 8 + pl;
        float p = 0.0f;
        #pragma unroll
        for (int ty = 0; ty < 3; ++ty) {
            int py = y + ty - 1;
            #pragma unroll
            for (int tx = 0; tx < 3; ++tx) {
                int px = x + tx - 1;
                if ((unsigned)py < 256u && (unsigned)px < 256u) {
                    i32x4 v = *(const i32x4*)(actb +
                        (((size_t)(a << 16) + (py << 8) + px) << 7) + (o << 4));
                    const unsigned* dv = (const unsigned*)&v;
                    #pragma unroll
                    for (int k = 0; k < 4; ++k) {
                        unsigned d = dv[k];
                        float flo = __builtin_bit_cast(float, d << 16);
                        float fhi = __builtin_bit_cast(float, d & 0xFFFF0000u);
                        p = fmaf(flo, wr[2 * k + 0][ty * 3 + tx], p);
                        p = fmaf(fhi, wr[2 * k + 1][ty * 3 + tx], p);
                    }
                }
            }
        }
        p += __shfl_xor(p, 1, 64);
        p += __shfl_xor(p, 2, 64);
        p += __shfl_xor(p, 4, 64);
        if (o == 0) W_a[(size_t)(a << 16) + (y << 8) + x] = p + bias;
    }
}

// ---------------------------------------------------------------------------
__global__ void wy_kernel(const float* __restrict__ yv,
                          const int* __restrict__ actions,
                          const float* __restrict__ W_a,
                          float* __restrict__ Wy) {
    int b = blockIdx.x, x = threadIdx.x;
    int a = actions[b];
    const float* Wp = W_a + (size_t)a * 65536;
    const float* yb = yv + b * 256;
    float acc = 0.0f;
    #pragma unroll 8
    for (int h = 0; h < 256; ++h)
        acc = fmaf(yb[h], Wp[(size_t)h * 256 + x], acc);
    Wy[b * 256 + x] = acc;
}

// ---------------------------------------------------------------------------
__global__ void logits_kernel(const float* __restrict__ xv,
                              const void* __restrict__ mask,
                              const int* __restrict__ flag,
                              const float* __restrict__ Wy,
                              float* __restrict__ out) {
    int tid = threadIdx.x, lane = tid & 63, wave = tid >> 6;
    int b = blockIdx.y;
    int fl = *flag;
    float4 wy4 = *(const float4*)(Wy + b * 256 + lane * 4);
    const float* xb = xv + (size_t)b * 4096 * 256;
    int l0 = blockIdx.x * 128 + wave * 32;
    for (int li = 0; li < 32; ++li) {
        int l = l0 + li;
        const float4 x4 = *(const float4*)(xb + (size_t)l * 256 + lane * 4);
        float p = x4.x * wy4.x + x4.y * wy4.y + x4.z * wy4.z + x4.w * wy4.w;
        #pragma unroll
        for (int off = 32; off > 0; off >>= 1)
            p += __shfl_xor(p, off, 64);
        if (lane == 0) {
            size_t mi = (size_t)b * 4096 + l;
            bool msk;
            if (fl & 2)      msk = ((const float*)mask)[mi] != 0.0f;
            else if (fl & 1) msk = ((const unsigned char*)mask)[mi] != 0;
            else             msk = ((const int*)mask)[mi] != 0;
            out[mi] = msk ? -__builtin_inff() : p;
        }
    }
}

// ---------------------------------------------------------------------------
__global__ void softmax_kernel(float* __restrict__ out) {
    int b = blockIdx.x, tid = threadIdx.x;
    int lane = tid & 63, wid = tid >> 6;
    float* row = out + (size_t)b * 4096;
    float v[4];
    float m = -__builtin_inff();
    #pragma unroll
    for (int i = 0; i < 4; ++i) { v[i] = row[tid + i * 1024]; m = fmaxf(m, v[i]); }
    #pragma unroll
    for (int off = 32; off > 0; off >>= 1) m = fmaxf(m, __shfl_xor(m, off, 64));
    __shared__ float redm[16];
    __shared__ float reds[16];
    if (lane == 0) redm[wid] = m;
    __syncthreads();
    float M = redm[0];
    #pragma unroll
    for (int j = 1; j < 16; ++j) M = fmaxf(M, redm[j]);
    float s = 0.0f;
    #pragma unroll
    for (int i = 0; i < 4; ++i) { v[i] = expf(v[i] - M); s += v[i]; }
    #pragma unroll
    for (int off = 32; off > 0; off >>= 1) s += __shfl_xor(s, off, 64);
    if (lane == 0) reds[wid] = s;
    __syncthreads();
    float S = 0.0f;
    #pragma unroll
    for (int j = 0; j < 16; ++j) S += reds[j];
    float inv = 1.0f / S;
    #pragma unroll
    for (int i = 0; i < 4; ++i) row[tid + i * 1024] = v[i] * inv;
}

// ---------------------------------------------------------------------------
extern "C" void kernel_launch(void* const* d_in, const int* in_sizes, int n_in,
                              void* d_out, int out_size, void* d_ws, size_t ws_size,
                              hipStream_t stream) {
    const float* xv      = (const float*)d_in[0];
    const float* yv      = (const float*)d_in[1];
    const void*  xmask   = d_in[2];
    const int*   actions = (const int*)d_in[3];
    const float* weight  = (const float*)d_in[4];
    const float* cw0 = (const float*)d_in[5];
    const float* cb0 = (const float*)d_in[6];
    const float* cw1 = (const float*)d_in[7];
    const float* cb1 = (const float*)d_in[8];
    const float* cw2 = (const float*)d_in[9];
    const float* cb2 = (const float*)d_in[10];
    const float* cw3 = (const float*)d_in[11];
    const float* cb3 = (const float*)d_in[12];
    const float* cw4 = (const float*)d_in[13];
    const float* cb4 = (const float*)d_in[14];
    float* out = (float*)d_out;

    char* ws = (char*)d_ws;
    unsigned short* bufA = (unsigned short*)ws;                    // 33554432 B
    unsigned short* bufB = (unsigned short*)(ws + 33554432);       // 33554432 B
    char*  apack = ws + 67108864;                                  // 3 x 294912 B
    float* W_a   = (float*)(ws + 67993600);                        // 1048576 B
    float* Wy    = (float*)(ws + 69042176);                        // 32768 B
    int*   flag  = (int*)(ws + 69074944);

    prep_kernel<<<1241, 256, 0, stream>>>(weight, cw0, cb0, bufA,
                                          cw1, cw2, cw3, apack,
                                          (const unsigned int*)xmask, flag);

    conv_mid_mfma<<<dim3(16, 32, 4), 256, 0, stream>>>(bufA, apack,          cb1, bufB);
    conv_mid_mfma<<<dim3(16, 32, 4), 256, 0, stream>>>(bufB, apack + 294912, cb2, bufA);
    conv_mid_mfma<<<dim3(16, 32, 4), 256, 0, stream>>>(bufA, apack + 589824, cb3, bufB);
    conv_last_kernel<<<dim3(256, 4), 256, 0, stream>>>(bufB, cw4, cb4, W_a);

    wy_kernel<<<32, 256, 0, stream>>>(yv, actions, W_a, Wy);
    logits_kernel<<<dim3(32, 32), 256, 0, stream>>>(xv, xmask, flag, Wy, out);
    softmax_kernel<<<32, 1024, 0, stream>>>(out);
}

// Round 4
// 406.652 us; speedup vs baseline: 1.0746x; 1.0746x over previous
//
#include <hip/hip_runtime.h>
#include <cstdint>
#include <cstddef>

typedef __attribute__((ext_vector_type(8))) short bf16x8;
typedef __attribute__((ext_vector_type(4))) float f32x4;
typedef __attribute__((ext_vector_type(4))) int i32x4;

// conv_mid tile geometry
#define MW  18            // halo width  (16 + 2)
#define MH  26            // halo height (24 + 2)
#define MPX (MW * MH)     // 468 pixels
#define MPP 469           // LDS plane stride in i32x4 (odd -> 20*o bank spread)

// conv_last tile geometry
#define LW  18
#define LPX (LW * LW)     // 324
#define LPP 325

__device__ inline unsigned short cvt_bf16_rne(float f) {
    unsigned u = __builtin_bit_cast(unsigned, f);
    u = (u + 0x7FFFu + ((u >> 16) & 1u)) >> 16;
    return (unsigned short)u;
}

// ---------------------------------------------------------------------------
// prep_kernel: fused conv_first (blocks 0..1023) + weight pack for layers
// 1..3 (blocks 1024..1239) + mask-format detect (block 1240). 256 threads.
__global__ void prep_kernel(const float* __restrict__ img,
                            const float* __restrict__ cw0,
                            const float* __restrict__ cb0,
                            unsigned short* __restrict__ act,
                            const float* __restrict__ cw1,
                            const float* __restrict__ cw2,
                            const float* __restrict__ cw3,
                            char* __restrict__ apack,
                            const unsigned int* __restrict__ mask,
                            int* __restrict__ flag) {
    int bid = blockIdx.x, tid = threadIdx.x;

    if (bid < 1024) {
        int y = bid & 255, a = bid >> 8, x = tid;
        float p[3][3];
        #pragma unroll
        for (int ty = 0; ty < 3; ++ty)
            #pragma unroll
            for (int tx = 0; tx < 3; ++tx) {
                int py = y + ty - 1, px = x + tx - 1;
                p[ty][tx] = ((unsigned)py < 256u && (unsigned)px < 256u)
                            ? img[py * 256 + px] : 0.0f;
            }
        const float* w = cw0 + (size_t)a * 64 * 9;
        const float* b = cb0 + a * 64;
        unsigned pk[32];
        #pragma unroll
        for (int co = 0; co < 64; ++co) {
            const float* wc = w + co * 9;
            float acc = b[co];
            #pragma unroll
            for (int ty = 0; ty < 3; ++ty)
                #pragma unroll
                for (int tx = 0; tx < 3; ++tx)
                    acc = fmaf(wc[ty * 3 + tx], p[ty][tx], acc);
            acc = fmaxf(acc, 0.0f);
            unsigned short hv = cvt_bf16_rne(acc);
            if (co & 1) pk[co >> 1] |= ((unsigned)hv << 16);
            else        pk[co >> 1] = (unsigned)hv;
        }
        char* ob = (char*)act + (((size_t)(a << 16) + (y << 8) + x) << 7);
        #pragma unroll
        for (int k = 0; k < 8; ++k)
            *(i32x4*)(ob + k * 16) = *(i32x4*)&pk[k * 4];
        return;
    }

    if (bid < 1240) {
        // A-frag pack: idx = (((a*2+ks)*9+tap)*4+mf)*64+lane, per layer.
        int idx = (bid - 1024) * 256 + tid;     // 0 .. 55295
        int layer = idx / 18432;
        int r = idx - layer * 18432;
        int lane = r & 63, mf = (r >> 6) & 3;
        int t = r >> 8;
        int tap = t % 9, t2 = t / 9;
        int ks = t2 & 1, a = t2 >> 1;
        int n = lane & 15, q = lane >> 4;
        int co = mf * 16 + n;
        int ci0 = ks * 32 + q * 8;
        const float* cw = (layer == 0) ? cw1 : (layer == 1) ? cw2 : cw3;
        unsigned d[4];
        #pragma unroll
        for (int jj = 0; jj < 4; ++jj) {
            unsigned short h0 = cvt_bf16_rne(cw[((size_t)(a * 64 + co) * 64 + ci0 + 2 * jj + 0) * 9 + tap]);
            unsigned short h1 = cvt_bf16_rne(cw[((size_t)(a * 64 + co) * 64 + ci0 + 2 * jj + 1) * 9 + tap]);
            d[jj] = (unsigned)h0 | ((unsigned)h1 << 16);
        }
        *(i32x4*)(apack + (size_t)idx * 16) = *(i32x4*)d;
        return;
    }

    // mask format detect: 0=int32, 1=bytes, 2=float
    __shared__ int red;
    if (tid == 0) red = 0;
    __syncthreads();
    int f = 0;
    for (int k = 0; k < 128; ++k) {
        unsigned v = mask[k * 256 + tid];
        if (v == 0x3F800000u) f |= 2;
        else if (v > 1u) f |= 1;
    }
    if (f) atomicOr(&red, f);
    __syncthreads();
    if (tid == 0) *flag = red;
}

// ---------------------------------------------------------------------------
// Mid layers 64->64 + ReLU via bf16 MFMA implicit GEMM.
// WG = 256 thr (4 waves); wave = 6 rows x 16 cols (nf=6), WG tile 24x16.
// A-frags: 4 per (ks,tap) for 24 MFMA -> 170 B/MFMA L2 demand (in budget).
// LDS: octet-major halo 26x18, plane stride 469 i32x4 (conflict-free b128).
// grid dim3(16, 11, 4) = 704 WGs.
__global__ __launch_bounds__(256, 2)
void conv_mid_mfma(const unsigned short* __restrict__ act_in,
                   const char* __restrict__ apack_l,
                   const float* __restrict__ cb,
                   unsigned short* __restrict__ act_out) {
    __shared__ i32x4 lds4[8 * MPP];   // 60032 B
    int tid = threadIdx.x;
    int a = blockIdx.z;
    int r0 = blockIdx.y * 24, c0 = blockIdx.x * 16;
    const char* actb = (const char*)act_in;

    for (int s = tid; s < 8 * MPX; s += 256) {
        int o = s & 7, px = s >> 3;
        int prow = px / MW, pcol = px - prow * MW;
        int grow = r0 - 1 + prow, gcol = c0 - 1 + pcol;
        i32x4 v = {0, 0, 0, 0};
        if ((unsigned)grow < 256u && (unsigned)gcol < 256u)
            v = *(const i32x4*)(actb + (((size_t)(a << 16) + (grow << 8) + gcol) << 7) + (o << 4));
        lds4[o * MPP + px] = v;
    }
    __syncthreads();

    int lane = tid & 63, wv = tid >> 6;
    int n = lane & 15, q = lane >> 4;
    int rbase = wv * 6;

    f32x4 acc[4][6];
    #pragma unroll
    for (int mf = 0; mf < 4; ++mf) {
        f32x4 bb = *(const f32x4*)(cb + a * 64 + mf * 16 + q * 4);
        #pragma unroll
        for (int nf = 0; nf < 6; ++nf) acc[mf][nf] = bb;
    }

    const char* ap = apack_l + (size_t)a * 73728 + lane * 16;
    // single B address base; every read is base + compile-time imm
    const i32x4* bbase = lds4 + q * MPP + rbase * MW + n;

    #pragma unroll
    for (int ks = 0; ks < 2; ++ks) {
        const char* apk = ap + ks * 36864;
        const i32x4* bks = bbase + ks * 4 * MPP;
        #pragma unroll
        for (int tap = 0; tap < 9; ++tap) {
            const int ty = tap / 3, tx = tap - ty * 3;
            bf16x8 Af[4], Bf[6];
            #pragma unroll
            for (int mf = 0; mf < 4; ++mf)
                Af[mf] = __builtin_bit_cast(bf16x8,
                    *(const i32x4*)(apk + tap * 4096 + mf * 1024));
            #pragma unroll
            for (int nf = 0; nf < 6; ++nf)
                Bf[nf] = __builtin_bit_cast(bf16x8, bks[(nf + ty) * MW + tx]);
            #pragma unroll
            for (int mf = 0; mf < 4; ++mf)
                #pragma unroll
                for (int nf = 0; nf < 6; ++nf)
                    acc[mf][nf] = __builtin_amdgcn_mfma_f32_16x16x32_bf16(
                        Af[mf], Bf[nf], acc[mf][nf], 0, 0, 0);
        }
    }

    #pragma unroll
    for (int nf = 0; nf < 6; ++nf) {
        int grow = r0 + rbase + nf;
        if (grow < 256) {
            int gcol = c0 + n;
            char* ob = (char*)act_out + (((size_t)(a << 16) + (grow << 8) + gcol) << 7) + q * 8;
            #pragma unroll
            for (int mf = 0; mf < 4; ++mf) {
                f32x4 v = acc[mf][nf];
                unsigned d0 = (unsigned)cvt_bf16_rne(fmaxf(v.x, 0.0f))
                            | ((unsigned)cvt_bf16_rne(fmaxf(v.y, 0.0f)) << 16);
                unsigned d1 = (unsigned)cvt_bf16_rne(fmaxf(v.z, 0.0f))
                            | ((unsigned)cvt_bf16_rne(fmaxf(v.w, 0.0f)) << 16);
                uint2 st; st.x = d0; st.y = d1;
                *(uint2*)(ob + mf * 32) = st;
            }
        }
    }
}

// ---------------------------------------------------------------------------
// Layer 4: 64 -> 1, no ReLU, fp32 out. LDS-tiled: 16x16 px tile, 18x18 halo
// staged once (octet-major, stride 325). 8 lanes per pixel, width-8 shuffle
// reduce. grid dim3(16, 16, 4), 256 threads.
__global__ __launch_bounds__(256, 3)
void conv_last_kernel(const unsigned short* __restrict__ act,
                      const float* __restrict__ cw4,
                      const float* __restrict__ cb4,
                      float* __restrict__ W_a) {
    __shared__ i32x4 lds4[8 * LPP];   // 41600 B
    int tid = threadIdx.x;
    int a = blockIdx.z;
    int r0 = blockIdx.y * 16, c0 = blockIdx.x * 16;
    const char* actb = (const char*)act;

    for (int s = tid; s < 8 * LPX; s += 256) {
        int o = s & 7, px = s >> 3;
        int prow = px / LW, pcol = px - prow * LW;
        int grow = r0 - 1 + prow, gcol = c0 - 1 + pcol;
        i32x4 v = {0, 0, 0, 0};
        if ((unsigned)grow < 256u && (unsigned)gcol < 256u)
            v = *(const i32x4*)(actb + (((size_t)(a << 16) + (grow << 8) + gcol) << 7) + (o << 4));
        lds4[o * LPP + px] = v;
    }
    __syncthreads();

    int lane = tid & 63, wv = tid >> 6;
    int o = lane & 7, pl = lane >> 3;

    float wr[8][9];
    #pragma unroll
    for (int j = 0; j < 8; ++j) {
        const float* wp = cw4 + ((size_t)a * 64 + o * 8 + j) * 9;
        #pragma unroll
        for (int t = 0; t < 9; ++t) wr[j][t] = wp[t];
    }
    float bias = cb4[a];
    const i32x4* lbase = lds4 + o * LPP;

    #pragma unroll
    for (int i = 0; i < 8; ++i) {
        // pixel within tile: linear = i*32 + wv*8 + pl
        int r = 2 * i + (wv >> 1);
        int c = ((wv & 1) << 3) + pl;
        float p = 0.0f;
        #pragma unroll
        for (int ty = 0; ty < 3; ++ty)
            #pragma unroll
            for (int tx = 0; tx < 3; ++tx) {
                i32x4 v = lbase[(r + ty) * LW + (c + tx)];
                const unsigned* dv = (const unsigned*)&v;
                #pragma unroll
                for (int k = 0; k < 4; ++k) {
                    unsigned d = dv[k];
                    float flo = __builtin_bit_cast(float, d << 16);
                    float fhi = __builtin_bit_cast(float, d & 0xFFFF0000u);
                    p = fmaf(flo, wr[2 * k + 0][ty * 3 + tx], p);
                    p = fmaf(fhi, wr[2 * k + 1][ty * 3 + tx], p);
                }
            }
        p += __shfl_xor(p, 1, 64);
        p += __shfl_xor(p, 2, 64);
        p += __shfl_xor(p, 4, 64);
        if (o == 0)
            W_a[(size_t)(a << 16) + ((r0 + r) << 8) + (c0 + c)] = p + bias;
    }
}

// ---------------------------------------------------------------------------
__global__ void wy_kernel(const float* __restrict__ yv,
                          const int* __restrict__ actions,
                          const float* __restrict__ W_a,
                          float* __restrict__ Wy) {
    int b = blockIdx.x, x = threadIdx.x;
    int a = actions[b];
    const float* Wp = W_a + (size_t)a * 65536;
    const float* yb = yv + b * 256;
    float acc = 0.0f;
    #pragma unroll 8
    for (int h = 0; h < 256; ++h)
        acc = fmaf(yb[h], Wp[(size_t)h * 256 + x], acc);
    Wy[b * 256 + x] = acc;
}

// ---------------------------------------------------------------------------
__global__ void logits_kernel(const float* __restrict__ xv,
                              const void* __restrict__ mask,
                              const int* __restrict__ flag,
                              const float* __restrict__ Wy,
                              float* __restrict__ out) {
    int tid = threadIdx.x, lane = tid & 63, wave = tid >> 6;
    int b = blockIdx.y;
    int fl = *flag;
    float4 wy4 = *(const float4*)(Wy + b * 256 + lane * 4);
    const float* xb = xv + (size_t)b * 4096 * 256;
    int l0 = blockIdx.x * 128 + wave * 32;
    for (int li = 0; li < 32; ++li) {
        int l = l0 + li;
        const float4 x4 = *(const float4*)(xb + (size_t)l * 256 + lane * 4);
        float p = x4.x * wy4.x + x4.y * wy4.y + x4.z * wy4.z + x4.w * wy4.w;
        #pragma unroll
        for (int off = 32; off > 0; off >>= 1)
            p += __shfl_xor(p, off, 64);
        if (lane == 0) {
            size_t mi = (size_t)b * 4096 + l;
            bool msk;
            if (fl & 2)      msk = ((const float*)mask)[mi] != 0.0f;
            else if (fl & 1) msk = ((const unsigned char*)mask)[mi] != 0;
            else             msk = ((const int*)mask)[mi] != 0;
            out[mi] = msk ? -__builtin_inff() : p;
        }
    }
}

// ---------------------------------------------------------------------------
__global__ void softmax_kernel(float* __restrict__ out) {
    int b = blockIdx.x, tid = threadIdx.x;
    int lane = tid & 63, wid = tid >> 6;
    float* row = out + (size_t)b * 4096;
    float v[4];
    float m = -__builtin_inff();
    #pragma unroll
    for (int i = 0; i < 4; ++i) { v[i] = row[tid + i * 1024]; m = fmaxf(m, v[i]); }
    #pragma unroll
    for (int off = 32; off > 0; off >>= 1) m = fmaxf(m, __shfl_xor(m, off, 64));
    __shared__ float redm[16];
    __shared__ float reds[16];
    if (lane == 0) redm[wid] = m;
    __syncthreads();
    float M = redm[0];
    #pragma unroll
    for (int j = 1; j < 16; ++j) M = fmaxf(M, redm[j]);
    float s = 0.0f;
    #pragma unroll
    for (int i = 0; i < 4; ++i) { v[i] = expf(v[i] - M); s += v[i]; }
    #pragma unroll
    for (int off = 32; off > 0; off >>= 1) s += __shfl_xor(s, off, 64);
    if (lane == 0) reds[wid] = s;
    __syncthreads();
    float S = 0.0f;
    #pragma unroll
    for (int j = 0; j < 16; ++j) S += reds[j];
    float inv = 1.0f / S;
    #pragma unroll
    for (int i = 0; i < 4; ++i) row[tid + i * 1024] = v[i] * inv;
}

// ---------------------------------------------------------------------------
extern "C" void kernel_launch(void* const* d_in, const int* in_sizes, int n_in,
                              void* d_out, int out_size, void* d_ws, size_t ws_size,
                              hipStream_t stream) {
    const float* xv      = (const float*)d_in[0];
    const float* yv      = (const float*)d_in[1];
    const void*  xmask   = d_in[2];
    const int*   actions = (const int*)d_in[3];
    const float* weight  = (const float*)d_in[4];
    const float* cw0 = (const float*)d_in[5];
    const float* cb0 = (const float*)d_in[6];
    const float* cw1 = (const float*)d_in[7];
    const float* cb1 = (const float*)d_in[8];
    const float* cw2 = (const float*)d_in[9];
    const float* cb2 = (const float*)d_in[10];
    const float* cw3 = (const float*)d_in[11];
    const float* cb3 = (const float*)d_in[12];
    const float* cw4 = (const float*)d_in[13];
    const float* cb4 = (const float*)d_in[14];
    float* out = (float*)d_out;

    char* ws = (char*)d_ws;
    unsigned short* bufA = (unsigned short*)ws;                    // 33554432 B
    unsigned short* bufB = (unsigned short*)(ws + 33554432);       // 33554432 B
    char*  apack = ws + 67108864;                                  // 3 x 294912 B
    float* W_a   = (float*)(ws + 67993600);                        // 1048576 B
    float* Wy    = (float*)(ws + 69042176);                        // 32768 B
    int*   flag  = (int*)(ws + 69074944);

    prep_kernel<<<1241, 256, 0, stream>>>(weight, cw0, cb0, bufA,
                                          cw1, cw2, cw3, apack,
                                          (const unsigned int*)xmask, flag);

    conv_mid_mfma<<<dim3(16, 11, 4), 256, 0, stream>>>(bufA, apack,          cb1, bufB);
    conv_mid_mfma<<<dim3(16, 11, 4), 256, 0, stream>>>(bufB, apack + 294912, cb2, bufA);
    conv_mid_mfma<<<dim3(16, 11, 4), 256, 0, stream>>>(bufA, apack + 589824, cb3, bufB);
    conv_last_kernel<<<dim3(16, 16, 4), 256, 0, stream>>>(bufB, cw4, cb4, W_a);

    wy_kernel<<<32, 256, 0, stream>>>(yv, actions, W_a, Wy);
    logits_kernel<<<dim3(32, 32), 256, 0, stream>>>(xv, xmask, flag, Wy, out);
    softmax_kernel<<<32, 1024, 0, stream>>>(out);
}